// Round 1
// baseline (990.384 us; speedup 1.0000x reference)
//
#include <hip/hip_runtime.h>
#include <hip/hip_bf16.h>

#define B_  256
#define N_  32768
#define D_  1024
#define H_  16
#define DH_ 64
#define KSPLIT 64
#define STRIPE (N_ / KSPLIT)   // 512 keys per split

typedef __attribute__((ext_vector_type(8))) short bf16x8;
typedef __attribute__((ext_vector_type(4))) float f32x4;

static __device__ __forceinline__ short f2bf(float f) {
    union { __hip_bfloat16 h; short s; } u;
    u.h = __float2bfloat16(f);
    return u.s;
}

static __device__ __forceinline__ bf16x8 pack8(float4 a, float4 b) {
    bf16x8 r;
    r[0] = f2bf(a.x); r[1] = f2bf(a.y); r[2] = f2bf(a.z); r[3] = f2bf(a.w);
    r[4] = f2bf(b.x); r[5] = f2bf(b.y); r[6] = f2bf(b.z); r[7] = f2bf(b.w);
    return r;
}

// async global->LDS DMA, 16B/lane, contiguous lane order (coalesced)
static __device__ __forceinline__ void gload16(const void* g, void* l) {
    __builtin_amdgcn_global_load_lds(
        (const __attribute__((address_space(1))) void*)g,
        (__attribute__((address_space(3))) void*)l, 16, 0, 0);
}

// ---------------------------------------------------------------------------
// f32 -> bf16: 8 elems/thread, 16B stores. n8 = elements/8.
// ---------------------------------------------------------------------------
__global__ __launch_bounds__(256)
void f2b_kernel(const float* __restrict__ in, short* __restrict__ out, int n8)
{
    int i = blockIdx.x * 256 + threadIdx.x;
    if (i < n8) {
        float4 a = ((const float4*)in)[2 * i];
        float4 b = ((const float4*)in)[2 * i + 1];
        ((bf16x8*)out)[i] = pack8(a, b);
    }
}

// ---------------------------------------------------------------------------
// Pure-bf16 GEMM (m97 clone): C = alpha * P[MP,K] x Qb[MQ,K]^T, both bf16.
// 128x128 tile, BK=32, LDS 8+8 KB contiguous (DMA-staged, coalesced),
// 4 waves x 4x4 16x16x32 MFMA.  XCD swizzle: p-stripe per XCD, q-fast.
// SWAP=false: C[p][q];  SWAP=true: C[q][p] (transposed V projection).
// ---------------------------------------------------------------------------
template<bool SWAP>
__global__ __launch_bounds__(256, 2)
void gemm_bb(const short* __restrict__ P, const short* __restrict__ Qb,
             short* __restrict__ C, int MP, int MQ, int K, int ldc, float alpha)
{
    __shared__ __align__(16) short Ps_[128 * 32];   // 8 KB
    __shared__ __align__(16) short Qs_[128 * 32];   // 8 KB

    const int tid  = threadIdx.x;
    const int wave = tid >> 6;
    const int lane = tid & 63;
    const int quad = lane >> 4;
    const int l16  = lane & 15;

    const int gp = MP >> 7, gq = MQ >> 7;
    const int bid = blockIdx.x;
    int bp, bq;
    if (gp >= 8) {
        int xcd = bid & 7, w = bid >> 3, sp = gp >> 3;
        bp = xcd * sp + w / gq;
        bq = w % gq;
    } else { bp = bid / gq; bq = bid % gq; }

    const int wm = (wave & 1) * 64;
    const int wn = (wave >> 1) * 64;

    // staging: 512 granules (16B) per tile, 2 per thread per tile; contiguous
    const char* gP[2]; char* lP[2];
    const char* gW[2]; char* lW[2];
#pragma unroll
    for (int j = 0; j < 2; ++j) {
        int s = j * 256 + tid;           // slot 0..511
        int r = s >> 2, g = s & 3;       // row, 16B-granule in 64B row
        gP[j] = (const char*)(P + (size_t)(bp * 128 + r) * K) + g * 16;
        lP[j] = (char*)Ps_ + s * 16;
        gW[j] = (const char*)(Qb + (size_t)(bq * 128 + r) * K) + g * 16;
        lW[j] = (char*)Qs_ + s * 16;
    }

    const short* tileA = SWAP ? Qs_ : Ps_;
    const short* tileB = SWAP ? Ps_ : Qs_;

    f32x4 acc[4][4];
#pragma unroll
    for (int i = 0; i < 4; ++i)
#pragma unroll
        for (int j = 0; j < 4; ++j) acc[i][j] = (f32x4){0.f, 0.f, 0.f, 0.f};

    for (int kt = 0; kt < K; kt += 32) {
        __syncthreads();
#pragma unroll
        for (int j = 0; j < 2; ++j) {
            gload16(gP[j], lP[j]); gP[j] += 64;
            gload16(gW[j], lW[j]); gW[j] += 64;
        }
        __syncthreads();

        bf16x8 af[4], bf[4];
#pragma unroll
        for (int f = 0; f < 4; ++f) {
            af[f] = *(const bf16x8*)&tileA[(wm + f * 16 + l16) * 32 + quad * 8];
            bf[f] = *(const bf16x8*)&tileB[(wn + f * 16 + l16) * 32 + quad * 8];
        }
#pragma unroll
        for (int mi = 0; mi < 4; ++mi)
#pragma unroll
            for (int ni = 0; ni < 4; ++ni)
                acc[mi][ni] = __builtin_amdgcn_mfma_f32_16x16x32_bf16(
                    af[mi], bf[ni], acc[mi][ni], 0, 0, 0);
    }

    // C/D layout: col = lane&15, row = quad*4 + reg  [m89-verified]
    const int rb = (SWAP ? bq : bp) * 128;
    const int cb = (SWAP ? bp : bq) * 128;
#pragma unroll
    for (int mi = 0; mi < 4; ++mi)
#pragma unroll
        for (int ni = 0; ni < 4; ++ni)
#pragma unroll
            for (int reg = 0; reg < 4; ++reg) {
                int r = rb + wm + mi * 16 + quad * 4 + reg;
                int c = cb + wn + ni * 16 + l16;
                C[(size_t)r * ldc + c] = f2bf(acc[mi][ni][reg] * alpha);
            }
}

// ---------------------------------------------------------------------------
// Flash attention, transposed-score, log2-domain softmax (qh pre-scaled by
// 1/8*log2e).  Grid (KSPLIT, 16 heads) = 1024 blocks -> 4 blocks/CU,
// 4 independent waves x 32 q-rows.  Both q-halves (qb2) per block so K/V
// frags are loaded ONCE.  Defer-max (T13): skip O-rescale when the running
// max doesn't grow by >8 (log2 domain; P bounded by 2^8, bf16-safe).
// ---------------------------------------------------------------------------
__global__ __launch_bounds__(256, 4)
void attn_kernel(const short* __restrict__ qh, const short* __restrict__ kh,
                 const short* __restrict__ vhT, float* __restrict__ partO,
                 float* __restrict__ partM, float* __restrict__ partL)
{
    const int st = blockIdx.x, h = blockIdx.y;
    const int tid  = threadIdx.x;
    const int wave = tid >> 6;
    const int lane = tid & 63;
    const int quad = lane >> 4;
    const int l16  = lane & 15;

    __shared__ __align__(16) short Ps[4][32][72];   // per-wave P round-trip

    const int hoff = h * DH_;

    // Q fragments for both halves (L2-hot, hoisted)
    bf16x8 qfr[2][2][2];   // [qb2][qf][ks]
#pragma unroll
    for (int qb2 = 0; qb2 < 2; ++qb2)
#pragma unroll
        for (int qf = 0; qf < 2; ++qf)
#pragma unroll
            for (int ks = 0; ks < 2; ++ks)
                qfr[qb2][qf][ks] = *(const bf16x8*)
                    (qh + (size_t)(qb2 * 128 + wave * 32 + qf * 16 + l16) * D_
                        + hoff + ks * 32 + quad * 8);

    f32x4 ofrag[2][2][4];
    float m_i[2][2], l_i[2][2];
#pragma unroll
    for (int qb2 = 0; qb2 < 2; ++qb2)
#pragma unroll
        for (int qf = 0; qf < 2; ++qf) {
            m_i[qb2][qf] = -__builtin_inff();
            l_i[qb2][qf] = 0.f;
#pragma unroll
            for (int dt = 0; dt < 4; ++dt) ofrag[qb2][qf][dt] = (f32x4){0.f,0.f,0.f,0.f};
        }

    const int n0 = st * STRIPE;

    for (int ch = 0; ch < STRIPE; ch += 64) {
        const int nb = n0 + ch;

        // K and V fragments for this chunk (shared across both q-halves)
        bf16x8 akf[4][2], avf[4][2];
#pragma unroll
        for (int kf = 0; kf < 4; ++kf)
#pragma unroll
            for (int ks = 0; ks < 2; ++ks)
                akf[kf][ks] = *(const bf16x8*)(kh + (size_t)(nb + kf * 16 + l16) * D_
                                               + hoff + ks * 32 + quad * 8);
#pragma unroll
        for (int dt = 0; dt < 4; ++dt)
#pragma unroll
            for (int g = 0; g < 2; ++g)
                avf[dt][g] = *(const bf16x8*)(vhT + (size_t)(hoff + dt * 16 + l16) * N_
                                              + nb + g * 32 + quad * 8);

#pragma unroll
        for (int qb2 = 0; qb2 < 2; ++qb2) {
            // S^T = K·Q^T
            f32x4 sf[4][2];
#pragma unroll
            for (int kf = 0; kf < 4; ++kf)
#pragma unroll
                for (int qf = 0; qf < 2; ++qf) sf[kf][qf] = (f32x4){0.f,0.f,0.f,0.f};
#pragma unroll
            for (int ks = 0; ks < 2; ++ks)
#pragma unroll
                for (int kf = 0; kf < 4; ++kf)
#pragma unroll
                    for (int qf = 0; qf < 2; ++qf)
                        sf[kf][qf] = __builtin_amdgcn_mfma_f32_16x16x32_bf16(
                            akf[kf][ks], qfr[qb2][qf][ks], sf[kf][qf], 0, 0, 0);

            // online softmax (log2 domain, defer-max)
#pragma unroll
            for (int qf = 0; qf < 2; ++qf) {
                float mx = sf[0][qf][0];
#pragma unroll
                for (int kf = 0; kf < 4; ++kf)
#pragma unroll
                    for (int r = 0; r < 4; ++r) mx = fmaxf(mx, sf[kf][qf][r]);
                mx = fmaxf(mx, __shfl_xor(mx, 16));
                mx = fmaxf(mx, __shfl_xor(mx, 32));
                const float mold = m_i[qb2][qf];
                // rescale only if some row's max grew by more than 8 (2^8 bound)
                if (!__all(mx - mold <= 8.f)) {
                    float mn = fmaxf(mold, mx);
                    float al = exp2f(mold - mn);
                    m_i[qb2][qf] = mn;
                    l_i[qb2][qf] *= al;
#pragma unroll
                    for (int dt = 0; dt < 4; ++dt) ofrag[qb2][qf][dt] *= al;
                }
                const float mn = m_i[qb2][qf];
                float ps = 0.f;
#pragma unroll
                for (int kf = 0; kf < 4; ++kf) {
                    float p0 = exp2f(sf[kf][qf][0] - mn);
                    float p1 = exp2f(sf[kf][qf][1] - mn);
                    float p2 = exp2f(sf[kf][qf][2] - mn);
                    float p3 = exp2f(sf[kf][qf][3] - mn);
                    ps += (p0 + p1) + (p2 + p3);
                    *(short4*)&Ps[wave][qf * 16 + l16][kf * 16 + quad * 4] =
                        make_short4(f2bf(p0), f2bf(p1), f2bf(p2), f2bf(p3));
                }
                ps += __shfl_xor(ps, 16);
                ps += __shfl_xor(ps, 32);
                l_i[qb2][qf] += ps;
            }

            // O^T += V·P   (per-wave LDS round-trip, no barrier)
#pragma unroll
            for (int qf = 0; qf < 2; ++qf)
#pragma unroll
                for (int g = 0; g < 2; ++g) {
                    bf16x8 bP = *(const bf16x8*)&Ps[wave][qf * 16 + l16][g * 32 + quad * 8];
#pragma unroll
                    for (int dt = 0; dt < 4; ++dt)
                        ofrag[qb2][qf][dt] = __builtin_amdgcn_mfma_f32_16x16x32_bf16(
                            avf[dt][g], bP, ofrag[qb2][qf][dt], 0, 0, 0);
                }
        }
    }

    const int pid = (h * KSPLIT + st) * 4 + wave;
#pragma unroll
    for (int qb2 = 0; qb2 < 2; ++qb2) {
        const size_t rowb = (size_t)(pid * 2 + qb2) * 32;
#pragma unroll
        for (int qf = 0; qf < 2; ++qf)
#pragma unroll
            for (int dt = 0; dt < 4; ++dt)
                *(f32x4*)&partO[(rowb + qf * 16 + l16) * 64 + dt * 16 + quad * 4]
                    = ofrag[qb2][qf][dt];
        if (quad == 0)
#pragma unroll
            for (int qf = 0; qf < 2; ++qf) {
                partM[rowb + qf * 16 + l16] = m_i[qb2][qf];
                partL[rowb + qf * 16 + l16] = l_i[qb2][qf];
            }
    }
}

// ---------------------------------------------------------------------------
// Merge KSPLIT partials (log2 domain).
// ---------------------------------------------------------------------------
__global__ __launch_bounds__(256)
void merge_kernel(const float* __restrict__ partO, const float* __restrict__ partM,
                  const float* __restrict__ partL, float* __restrict__ out)
{
    int idx = blockIdx.x * 256 + threadIdx.x;   // 0 .. B*D-1
    int b   = idx >> 10;
    int col = idx & 1023;
    int h   = col >> 6;
    int d   = col & 63;
    int qb2 = b >> 7, rr = b & 127;
    int w = rr >> 5, rin = rr & 31;

    float mmax = -__builtin_inff();
#pragma unroll
    for (int st = 0; st < KSPLIT; ++st) {
        int slot = (((h * KSPLIT + st) * 4 + w) * 2 + qb2) * 32 + rin;
        mmax = fmaxf(mmax, partM[slot]);
    }
    float L = 0.f, o = 0.f;
#pragma unroll
    for (int st = 0; st < KSPLIT; ++st) {
        int slot = (((h * KSPLIT + st) * 4 + w) * 2 + qb2) * 32 + rin;
        float c = exp2f(partM[slot] - mmax);
        L += c * partL[slot];
        o += c * partO[(size_t)slot * 64 + d];
    }
    out[idx] = o / L;
}

// ---------------------------------------------------------------------------
extern "C" void kernel_launch(void* const* d_in, const int* in_sizes, int n_in,
                              void* d_out, int out_size, void* d_ws, size_t ws_size,
                              hipStream_t stream) {
    const float* q   = (const float*)d_in[0];
    const float* k   = (const float*)d_in[1];
    const float* v   = (const float*)d_in[2];
    const float* W_q = (const float*)d_in[3];
    const float* W_k = (const float*)d_in[4];
    const float* W_v = (const float*)d_in[5];
    float* out = (float*)d_out;

    // workspace (~209 MB):
    //   [qh 0.5M][kh 67M][vhT 67M][kvb 67M][qb 0.5M][Wq 2M][Wk 2M][Wv 2M]
    // partials (69.2 MB) ALIAS [kvb..Wv end] (73.9 MB) — those regions are
    // dead after the last projection GEMM; stream order serializes.
    short* qh  = (short*)d_ws;                    // 256x1024 bf16
    short* kh  = qh  + (size_t)B_ * D_;           // 32768x1024 bf16
    short* vhT = kh  + (size_t)N_ * D_;           // 1024x32768 bf16
    short* kvb = vhT + (size_t)D_ * N_;           // reused bf16 input
    short* qb  = kvb + (size_t)N_ * D_;           // 256x1024 bf16
    short* Wqb = qb  + (size_t)B_ * D_;           // 3 x 2 MB bf16 weights
    short* Wkb = Wqb + (size_t)D_ * D_;
    short* Wvb = Wkb + (size_t)D_ * D_;
    float* partO = (float*)kvb;                   // 8192 x 32 x 64 f32 (67 MB)
    float* partM = partO + (size_t)H_ * KSPLIT * 4 * 2 * 32 * 64;
    float* partL = partM + (size_t)H_ * KSPLIT * 4 * 2 * 32;

    dim3 blk(256);
    const int w8  = (D_ * D_) / 8;     // weight: 131072 x 16B
    const int kv8 = (N_ * D_) / 8;     // k/v:    4194304 x 16B
    const int q8  = (B_ * D_) / 8;
    const float alpha_q = 0.125f * 1.4426950408889634f;  // 1/sqrt(64)*log2(e)

    f2b_kernel<<<dim3(w8 / 256), blk, 0, stream>>>(W_q, Wqb, w8);
    f2b_kernel<<<dim3(w8 / 256), blk, 0, stream>>>(W_k, Wkb, w8);
    f2b_kernel<<<dim3(w8 / 256), blk, 0, stream>>>(W_v, Wvb, w8);
    f2b_kernel<<<dim3(q8 / 256), blk, 0, stream>>>(q, qb, q8);

    // qh = (q @ W_q^T) * alpha_q
    gemm_bb<false><<<dim3(2 * 8), blk, 0, stream>>>(qb, Wqb, qh, B_, D_, D_, D_, alpha_q);

    // kh = k @ W_k^T
    f2b_kernel<<<dim3(kv8 / 256), blk, 0, stream>>>(k, kvb, kv8);
    gemm_bb<false><<<dim3(256 * 8), blk, 0, stream>>>(kvb, Wkb, kh, N_, D_, D_, D_, 1.0f);

    // vhT = (v @ W_v^T)^T   (kvb reused; stream order serializes)
    f2b_kernel<<<dim3(kv8 / 256), blk, 0, stream>>>(v, kvb, kv8);
    gemm_bb<true><<<dim3(256 * 8), blk, 0, stream>>>(kvb, Wvb, vhT, N_, D_, D_, N_, 1.0f);

    // partials may now alias kvb/qb/W* (all dead)
    attn_kernel<<<dim3(KSPLIT, H_), blk, 0, stream>>>(qh, kh, vhT, partO, partM, partL);
    merge_kernel<<<dim3((B_ * D_) / 256), blk, 0, stream>>>(partO, partM, partL, out);
}

// Round 2
// 585.265 us; speedup vs baseline: 1.6922x; 1.6922x over previous
//
#include <hip/hip_runtime.h>
#include <hip/hip_bf16.h>

#define B_  256
#define N_  32768
#define D_  1024
#define H_  16
#define DH_ 64
#define KSPLIT 64
#define STRIPE (N_ / KSPLIT)   // 512 keys per split

typedef __attribute__((ext_vector_type(8))) short bf16x8;
typedef __attribute__((ext_vector_type(4))) float f32x4;

static __device__ __forceinline__ short f2bf(float f) {
    union { __hip_bfloat16 h; short s; } u;
    u.h = __float2bfloat16(f);
    return u.s;
}

static __device__ __forceinline__ bf16x8 pack8(float4 a, float4 b) {
    bf16x8 r;
    r[0] = f2bf(a.x); r[1] = f2bf(a.y); r[2] = f2bf(a.z); r[3] = f2bf(a.w);
    r[4] = f2bf(b.x); r[5] = f2bf(b.y); r[6] = f2bf(b.z); r[7] = f2bf(b.w);
    return r;
}

// async global->LDS DMA, 16B/lane, contiguous lane order (coalesced)
static __device__ __forceinline__ void gload16(const void* g, void* l) {
    __builtin_amdgcn_global_load_lds(
        (const __attribute__((address_space(1))) void*)g,
        (__attribute__((address_space(3))) void*)l, 16, 0, 0);
}

// ---------------------------------------------------------------------------
// f32 -> bf16: 8 elems/thread, 16B stores. n8 = elements/8.
// ---------------------------------------------------------------------------
__global__ __launch_bounds__(256)
void f2b_kernel(const float* __restrict__ in, short* __restrict__ out, int n8)
{
    int i = blockIdx.x * 256 + threadIdx.x;
    if (i < n8) {
        float4 a = ((const float4*)in)[2 * i];
        float4 b = ((const float4*)in)[2 * i + 1];
        ((bf16x8*)out)[i] = pack8(a, b);
    }
}

// ---------------------------------------------------------------------------
// Pure-bf16 GEMM (m97 clone): C = alpha * P[MP,K] x Qb[MQ,K]^T, both bf16.
// 128x128 tile, BK=32, LDS 8+8 KB contiguous (DMA-staged, coalesced),
// 4 waves x 4x4 16x16x32 MFMA.  XCD swizzle: p-stripe per XCD, q-fast.
// SWAP=false: C[p][q];  SWAP=true: C[q][p] (transposed V projection).
// ---------------------------------------------------------------------------
template<bool SWAP>
__global__ __launch_bounds__(256, 2)
void gemm_bb(const short* __restrict__ P, const short* __restrict__ Qb,
             short* __restrict__ C, int MP, int MQ, int K, int ldc, float alpha)
{
    __shared__ __align__(16) short Ps_[128 * 32];   // 8 KB
    __shared__ __align__(16) short Qs_[128 * 32];   // 8 KB

    const int tid  = threadIdx.x;
    const int wave = tid >> 6;
    const int lane = tid & 63;
    const int quad = lane >> 4;
    const int l16  = lane & 15;

    const int gp = MP >> 7, gq = MQ >> 7;
    const int bid = blockIdx.x;
    int bp, bq;
    if (gp >= 8) {
        int xcd = bid & 7, w = bid >> 3, sp = gp >> 3;
        bp = xcd * sp + w / gq;
        bq = w % gq;
    } else { bp = bid / gq; bq = bid % gq; }

    const int wm = (wave & 1) * 64;
    const int wn = (wave >> 1) * 64;

    // staging: 512 granules (16B) per tile, 2 per thread per tile; contiguous
    const char* gP[2]; char* lP[2];
    const char* gW[2]; char* lW[2];
#pragma unroll
    for (int j = 0; j < 2; ++j) {
        int s = j * 256 + tid;           // slot 0..511
        int r = s >> 2, g = s & 3;       // row, 16B-granule in 64B row
        gP[j] = (const char*)(P + (size_t)(bp * 128 + r) * K) + g * 16;
        lP[j] = (char*)Ps_ + s * 16;
        gW[j] = (const char*)(Qb + (size_t)(bq * 128 + r) * K) + g * 16;
        lW[j] = (char*)Qs_ + s * 16;
    }

    const short* tileA = SWAP ? Qs_ : Ps_;
    const short* tileB = SWAP ? Ps_ : Qs_;

    f32x4 acc[4][4];
#pragma unroll
    for (int i = 0; i < 4; ++i)
#pragma unroll
        for (int j = 0; j < 4; ++j) acc[i][j] = (f32x4){0.f, 0.f, 0.f, 0.f};

    for (int kt = 0; kt < K; kt += 32) {
        __syncthreads();
#pragma unroll
        for (int j = 0; j < 2; ++j) {
            gload16(gP[j], lP[j]); gP[j] += 64;
            gload16(gW[j], lW[j]); gW[j] += 64;
        }
        __syncthreads();

        bf16x8 af[4], bf[4];
#pragma unroll
        for (int f = 0; f < 4; ++f) {
            af[f] = *(const bf16x8*)&tileA[(wm + f * 16 + l16) * 32 + quad * 8];
            bf[f] = *(const bf16x8*)&tileB[(wn + f * 16 + l16) * 32 + quad * 8];
        }
#pragma unroll
        for (int mi = 0; mi < 4; ++mi)
#pragma unroll
            for (int ni = 0; ni < 4; ++ni)
                acc[mi][ni] = __builtin_amdgcn_mfma_f32_16x16x32_bf16(
                    af[mi], bf[ni], acc[mi][ni], 0, 0, 0);
    }

    // C/D layout: col = lane&15, row = quad*4 + reg  [m89-verified]
    const int rb = (SWAP ? bq : bp) * 128;
    const int cb = (SWAP ? bp : bq) * 128;
#pragma unroll
    for (int mi = 0; mi < 4; ++mi)
#pragma unroll
        for (int ni = 0; ni < 4; ++ni)
#pragma unroll
            for (int reg = 0; reg < 4; ++reg) {
                int r = rb + wm + mi * 16 + quad * 4 + reg;
                int c = cb + wn + ni * 16 + l16;
                C[(size_t)r * ldc + c] = f2bf(acc[mi][ni][reg] * alpha);
            }
}

// ---------------------------------------------------------------------------
// Flash attention, transposed-score, log2-domain softmax (qh pre-scaled by
// 1/8*log2e).  Grid (KSPLIT, 16 heads) = 1024 blocks -> 4 blocks/CU,
// 4 independent waves x 32 q-rows.  Both q-halves (qb2) per block so K/V
// frags are loaded ONCE.  Defer-max (T13): skip O-rescale when the running
// max doesn't grow by >8 (log2 domain; P bounded by 2^8, bf16-safe).
// NOTE: launch_bounds must stay (256,2) — (256,4) makes the allocator split
// the unified reg file to 64 arch-VGPRs and spill ~1.7 GB to scratch (R1).
// ---------------------------------------------------------------------------
__global__ __launch_bounds__(256, 2)
void attn_kernel(const short* __restrict__ qh, const short* __restrict__ kh,
                 const short* __restrict__ vhT, float* __restrict__ partO,
                 float* __restrict__ partM, float* __restrict__ partL)
{
    const int st = blockIdx.x, h = blockIdx.y;
    const int tid  = threadIdx.x;
    const int wave = tid >> 6;
    const int lane = tid & 63;
    const int quad = lane >> 4;
    const int l16  = lane & 15;

    __shared__ __align__(16) short Ps[4][32][72];   // per-wave P round-trip

    const int hoff = h * DH_;

    // Q fragments for both halves (L2-hot, hoisted)
    bf16x8 qfr[2][2][2];   // [qb2][qf][ks]
#pragma unroll
    for (int qb2 = 0; qb2 < 2; ++qb2)
#pragma unroll
        for (int qf = 0; qf < 2; ++qf)
#pragma unroll
            for (int ks = 0; ks < 2; ++ks)
                qfr[qb2][qf][ks] = *(const bf16x8*)
                    (qh + (size_t)(qb2 * 128 + wave * 32 + qf * 16 + l16) * D_
                        + hoff + ks * 32 + quad * 8);

    f32x4 ofrag[2][2][4];
    float m_i[2][2], l_i[2][2];
#pragma unroll
    for (int qb2 = 0; qb2 < 2; ++qb2)
#pragma unroll
        for (int qf = 0; qf < 2; ++qf) {
            m_i[qb2][qf] = -__builtin_inff();
            l_i[qb2][qf] = 0.f;
#pragma unroll
            for (int dt = 0; dt < 4; ++dt) ofrag[qb2][qf][dt] = (f32x4){0.f,0.f,0.f,0.f};
        }

    const int n0 = st * STRIPE;

    for (int ch = 0; ch < STRIPE; ch += 64) {
        const int nb = n0 + ch;

        // K and V fragments for this chunk (shared across both q-halves)
        bf16x8 akf[4][2], avf[4][2];
#pragma unroll
        for (int kf = 0; kf < 4; ++kf)
#pragma unroll
            for (int ks = 0; ks < 2; ++ks)
                akf[kf][ks] = *(const bf16x8*)(kh + (size_t)(nb + kf * 16 + l16) * D_
                                               + hoff + ks * 32 + quad * 8);
#pragma unroll
        for (int dt = 0; dt < 4; ++dt)
#pragma unroll
            for (int g = 0; g < 2; ++g)
                avf[dt][g] = *(const bf16x8*)(vhT + (size_t)(hoff + dt * 16 + l16) * N_
                                              + nb + g * 32 + quad * 8);

#pragma unroll
        for (int qb2 = 0; qb2 < 2; ++qb2) {
            // S^T = K·Q^T
            f32x4 sf[4][2];
#pragma unroll
            for (int kf = 0; kf < 4; ++kf)
#pragma unroll
                for (int qf = 0; qf < 2; ++qf) sf[kf][qf] = (f32x4){0.f,0.f,0.f,0.f};
#pragma unroll
            for (int ks = 0; ks < 2; ++ks)
#pragma unroll
                for (int kf = 0; kf < 4; ++kf)
#pragma unroll
                    for (int qf = 0; qf < 2; ++qf)
                        sf[kf][qf] = __builtin_amdgcn_mfma_f32_16x16x32_bf16(
                            akf[kf][ks], qfr[qb2][qf][ks], sf[kf][qf], 0, 0, 0);

            // online softmax (log2 domain, defer-max)
#pragma unroll
            for (int qf = 0; qf < 2; ++qf) {
                float mx = sf[0][qf][0];
#pragma unroll
                for (int kf = 0; kf < 4; ++kf)
#pragma unroll
                    for (int r = 0; r < 4; ++r) mx = fmaxf(mx, sf[kf][qf][r]);
                mx = fmaxf(mx, __shfl_xor(mx, 16));
                mx = fmaxf(mx, __shfl_xor(mx, 32));
                const float mold = m_i[qb2][qf];
                // rescale only if some row's max grew by more than 8 (2^8 bound)
                if (!__all(mx - mold <= 8.f)) {
                    float mn = fmaxf(mold, mx);
                    float al = exp2f(mold - mn);
                    m_i[qb2][qf] = mn;
                    l_i[qb2][qf] *= al;
#pragma unroll
                    for (int dt = 0; dt < 4; ++dt) ofrag[qb2][qf][dt] *= al;
                }
                const float mn = m_i[qb2][qf];
                float ps = 0.f;
#pragma unroll
                for (int kf = 0; kf < 4; ++kf) {
                    float p0 = exp2f(sf[kf][qf][0] - mn);
                    float p1 = exp2f(sf[kf][qf][1] - mn);
                    float p2 = exp2f(sf[kf][qf][2] - mn);
                    float p3 = exp2f(sf[kf][qf][3] - mn);
                    ps += (p0 + p1) + (p2 + p3);
                    *(short4*)&Ps[wave][qf * 16 + l16][kf * 16 + quad * 4] =
                        make_short4(f2bf(p0), f2bf(p1), f2bf(p2), f2bf(p3));
                }
                ps += __shfl_xor(ps, 16);
                ps += __shfl_xor(ps, 32);
                l_i[qb2][qf] += ps;
            }

            // O^T += V·P   (per-wave LDS round-trip, no barrier)
#pragma unroll
            for (int qf = 0; qf < 2; ++qf)
#pragma unroll
                for (int g = 0; g < 2; ++g) {
                    bf16x8 bP = *(const bf16x8*)&Ps[wave][qf * 16 + l16][g * 32 + quad * 8];
#pragma unroll
                    for (int dt = 0; dt < 4; ++dt)
                        ofrag[qb2][qf][dt] = __builtin_amdgcn_mfma_f32_16x16x32_bf16(
                            avf[dt][g], bP, ofrag[qb2][qf][dt], 0, 0, 0);
                }
        }
    }

    const int pid = (h * KSPLIT + st) * 4 + wave;
#pragma unroll
    for (int qb2 = 0; qb2 < 2; ++qb2) {
        const size_t rowb = (size_t)(pid * 2 + qb2) * 32;
#pragma unroll
        for (int qf = 0; qf < 2; ++qf)
#pragma unroll
            for (int dt = 0; dt < 4; ++dt)
                *(f32x4*)&partO[(rowb + qf * 16 + l16) * 64 + dt * 16 + quad * 4]
                    = ofrag[qb2][qf][dt];
        if (quad == 0)
#pragma unroll
            for (int qf = 0; qf < 2; ++qf) {
                partM[rowb + qf * 16 + l16] = m_i[qb2][qf];
                partL[rowb + qf * 16 + l16] = l_i[qb2][qf];
            }
    }
}

// ---------------------------------------------------------------------------
// Merge KSPLIT partials (log2 domain).
// ---------------------------------------------------------------------------
__global__ __launch_bounds__(256)
void merge_kernel(const float* __restrict__ partO, const float* __restrict__ partM,
                  const float* __restrict__ partL, float* __restrict__ out)
{
    int idx = blockIdx.x * 256 + threadIdx.x;   // 0 .. B*D-1
    int b   = idx >> 10;
    int col = idx & 1023;
    int h   = col >> 6;
    int d   = col & 63;
    int qb2 = b >> 7, rr = b & 127;
    int w = rr >> 5, rin = rr & 31;

    float mmax = -__builtin_inff();
#pragma unroll
    for (int st = 0; st < KSPLIT; ++st) {
        int slot = (((h * KSPLIT + st) * 4 + w) * 2 + qb2) * 32 + rin;
        mmax = fmaxf(mmax, partM[slot]);
    }
    float L = 0.f, o = 0.f;
#pragma unroll
    for (int st = 0; st < KSPLIT; ++st) {
        int slot = (((h * KSPLIT + st) * 4 + w) * 2 + qb2) * 32 + rin;
        float c = exp2f(partM[slot] - mmax);
        L += c * partL[slot];
        o += c * partO[(size_t)slot * 64 + d];
    }
    out[idx] = o / L;
}

// ---------------------------------------------------------------------------
extern "C" void kernel_launch(void* const* d_in, const int* in_sizes, int n_in,
                              void* d_out, int out_size, void* d_ws, size_t ws_size,
                              hipStream_t stream) {
    const float* q   = (const float*)d_in[0];
    const float* k   = (const float*)d_in[1];
    const float* v   = (const float*)d_in[2];
    const float* W_q = (const float*)d_in[3];
    const float* W_k = (const float*)d_in[4];
    const float* W_v = (const float*)d_in[5];
    float* out = (float*)d_out;

    // workspace (~209 MB):
    //   [qh 0.5M][kh 67M][vhT 67M][kvb 67M][qb 0.5M][Wq 2M][Wk 2M][Wv 2M]
    // partials (69.2 MB) ALIAS [kvb..Wv end] (73.9 MB) — those regions are
    // dead after the last projection GEMM; stream order serializes.
    short* qh  = (short*)d_ws;                    // 256x1024 bf16
    short* kh  = qh  + (size_t)B_ * D_;           // 32768x1024 bf16
    short* vhT = kh  + (size_t)N_ * D_;           // 1024x32768 bf16
    short* kvb = vhT + (size_t)D_ * N_;           // reused bf16 input
    short* qb  = kvb + (size_t)N_ * D_;           // 256x1024 bf16
    short* Wqb = qb  + (size_t)B_ * D_;           // 3 x 2 MB bf16 weights
    short* Wkb = Wqb + (size_t)D_ * D_;
    short* Wvb = Wkb + (size_t)D_ * D_;
    float* partO = (float*)kvb;                   // 8192 x 32 x 64 f32 (67 MB)
    float* partM = partO + (size_t)H_ * KSPLIT * 4 * 2 * 32 * 64;
    float* partL = partM + (size_t)H_ * KSPLIT * 4 * 2 * 32;

    dim3 blk(256);
    const int w8  = (D_ * D_) / 8;     // weight: 131072 x 16B
    const int kv8 = (N_ * D_) / 8;     // k/v:    4194304 x 16B
    const int q8  = (B_ * D_) / 8;
    const float alpha_q = 0.125f * 1.4426950408889634f;  // 1/sqrt(64)*log2(e)

    f2b_kernel<<<dim3(w8 / 256), blk, 0, stream>>>(W_q, Wqb, w8);
    f2b_kernel<<<dim3(w8 / 256), blk, 0, stream>>>(W_k, Wkb, w8);
    f2b_kernel<<<dim3(w8 / 256), blk, 0, stream>>>(W_v, Wvb, w8);
    f2b_kernel<<<dim3(q8 / 256), blk, 0, stream>>>(q, qb, q8);

    // qh = (q @ W_q^T) * alpha_q
    gemm_bb<false><<<dim3(2 * 8), blk, 0, stream>>>(qb, Wqb, qh, B_, D_, D_, D_, alpha_q);

    // kh = k @ W_k^T
    f2b_kernel<<<dim3(kv8 / 256), blk, 0, stream>>>(k, kvb, kv8);
    gemm_bb<false><<<dim3(256 * 8), blk, 0, stream>>>(kvb, Wkb, kh, N_, D_, D_, D_, 1.0f);

    // vhT = (v @ W_v^T)^T   (kvb reused; stream order serializes)
    f2b_kernel<<<dim3(kv8 / 256), blk, 0, stream>>>(v, kvb, kv8);
    gemm_bb<true><<<dim3(256 * 8), blk, 0, stream>>>(kvb, Wvb, vhT, N_, D_, D_, N_, 1.0f);

    // partials may now alias kvb/qb/W* (all dead)
    attn_kernel<<<dim3(KSPLIT, H_), blk, 0, stream>>>(qh, kh, vhT, partO, partM, partL);
    merge_kernel<<<dim3((B_ * D_) / 256), blk, 0, stream>>>(partO, partM, partL, out);
}